// Round 3
// baseline (223.567 us; speedup 1.0000x reference)
//
#include <hip/hip_runtime.h>

// Haar DWT along axis 1 of (8, 4096, 1024) fp32.
// cA[b,j,c] = (x[b,2j,c] + x[b,2j+1,c]) * k,  cD = (x_even - x_odd) * k
// d_out = [cA flat | cD flat].
//
// Pure streaming (268 MB, zero reuse). A/B history on this problem:
//  r0: NT loads + NT stores, 4 rows, interleaved   -> kernel ~71.8 us
//  r1: cached loads + NT stores, 4 rows, hoisted   -> kernel  80.5 us (measured)
//  r2: NT loads + NT stores, 8 rows, hoisted       -> kernel ~71.1 us
// All stuck at ~3.8 TB/s effective vs 6.29 TB/s copy ceiling. Every config
// used NT stores; the plain-store fillBufferAligned sustains 6.75 TB/s on
// this chip. Hypothesis: nt stores bypass L2 write-coalescing and retire as
// narrow HBM bursts; plain stores allocate and evict as full lines.
// This round: NT loads (won its A/B) + PLAIN stores. Structure unchanged.

#define NPAIR (8 * 2048)        // total pair-rows
#define ROWS_PER_BLOCK 8
#define NPAIR_VEC (NPAIR * 256) // vec4 elements per output half

typedef float f4 __attribute__((ext_vector_type(4)));

__global__ __launch_bounds__(256) void dwt_haar_kernel(
    const f4* __restrict__ x,
    f4* __restrict__ cA,
    f4* __restrict__ cD)
{
    const float k = 0.7071067811865476f;
    const int t = threadIdx.x;                   // vec4 column 0..255
    const int r0 = blockIdx.x * ROWS_PER_BLOCK;  // first pair-row of block

    // Preload: 16 global_load_dwordx4 nt, issued back-to-back.
    f4 a[ROWS_PER_BLOCK], b[ROWS_PER_BLOCK];
#pragma unroll
    for (int j = 0; j < ROWS_PER_BLOCK; ++j) {
        const int e = (r0 + j) * 512 + t;        // even input row, vec4 units
        a[j] = __builtin_nontemporal_load(&x[e]);
        b[j] = __builtin_nontemporal_load(&x[e + 256]);
    }

    // Compute + store: PLAIN stores (allocate in L2, retire as full-line
    // writebacks — the 6.7 TB/s fill-kernel path).
#pragma unroll
    for (int j = 0; j < ROWS_PER_BLOCK; ++j) {
        const f4 s = (a[j] + b[j]) * k;
        const f4 d = (a[j] - b[j]) * k;
        const int o = (r0 + j) * 256 + t;
        cA[o] = s;
        cD[o] = d;
    }
}

extern "C" void kernel_launch(void* const* d_in, const int* in_sizes, int n_in,
                              void* d_out, int out_size, void* d_ws, size_t ws_size,
                              hipStream_t stream)
{
    const f4* x = (const f4*)d_in[0];
    f4* cA = (f4*)d_out;
    f4* cD = cA + NPAIR_VEC;

    const int nblocks = NPAIR / ROWS_PER_BLOCK;  // 2048 = 8 blocks/CU
    dwt_haar_kernel<<<nblocks, 256, 0, stream>>>(x, cA, cD);
}